// Round 1
// baseline (194.210 us; speedup 1.0000x reference)
//
#include <hip/hip_runtime.h>
#include <math.h>

#define SCALING 0.125f

typedef __attribute__((ext_vector_type(8))) short short8;
typedef __attribute__((ext_vector_type(4))) float f32x4;

// round-to-nearest-even fp32 -> bf16
static __device__ __forceinline__ unsigned short bf16r(float x) {
  unsigned int u = __float_as_uint(x);
  u += 0x7fffu + ((u >> 16) & 1u);
  return (unsigned short)(u >> 16);
}
static __device__ __forceinline__ float bf16f(unsigned short h) {
  return __uint_as_float(((unsigned int)h) << 16);
}
// pack two fp32 -> bf16x2 via v_perm_b32 merge
static __device__ __forceinline__ unsigned int pk_bf16(float lo, float hi) {
  unsigned int ua = __float_as_uint(lo);
  unsigned int ub = __float_as_uint(hi);
  ua += 0x7fffu + ((ua >> 16) & 1u);
  ub += 0x7fffu + ((ub >> 16) & 1u);
  return __builtin_amdgcn_perm(ub, ua, 0x07060302u);
}
// fp32x4 -> bf16 hi + residual lo
static __device__ __forceinline__ void split4(float4 x, ushort4& h, ushort4& l) {
  h.x = bf16r(x.x); l.x = bf16r(x.x - bf16f(h.x));
  h.y = bf16r(x.y); l.y = bf16r(x.y - bf16f(h.y));
  h.z = bf16r(x.z); l.z = bf16r(x.z - bf16f(h.z));
  h.w = bf16r(x.w); l.w = bf16r(x.w - bf16f(h.w));
}
union U4S8 { uint4 u; short8 s; };

// ---------------------------------------------------------------------------
// Kernel A: in-projection GEMM, hi/lo bf16 MFMA (verified R7/R8/R9). Unchanged.
// ---------------------------------------------------------------------------
__global__ __launch_bounds__(256)
void projmm_kernel(const float* __restrict__ query,
                   const float* __restrict__ key,
                   const float* __restrict__ value,
                   const float* __restrict__ W,
                   const float* __restrict__ bias,
                   float* __restrict__ qh, float* __restrict__ kh,
                   unsigned short* __restrict__ vh) {
  __shared__ __align__(16) unsigned short Ah[64 * 72];
  __shared__ __align__(16) unsigned short Al[64 * 72];
  __shared__ __align__(16) unsigned short Bh[64 * 72];
  __shared__ __align__(16) unsigned short Bl[64 * 72];
  const int n0 = blockIdx.x * 64;  // 0..1535
  const int g = n0 >> 9;           // 0=q,1=k,2=v
  const float* __restrict__ X = (g == 0) ? query : (g == 1) ? key : value;
  const int m0 = blockIdx.y * 64;
  const int tid = threadIdx.x;
  const int w = tid >> 6, lane = tid & 63;
  const int quad = lane >> 4, n15 = lane & 15;
  const int srow = tid >> 2;        // 0..63
  const int scol = (tid & 3) * 16;  // 0,16,32,48

  f32x4 acc[4];
#pragma unroll
  for (int nt = 0; nt < 4; ++nt) acc[nt] = (f32x4){0.f, 0.f, 0.f, 0.f};

  float4 av[4], bv[4];
#pragma unroll
  for (int jj = 0; jj < 4; ++jj) {
    av[jj] = *(const float4*)&X[(m0 + srow) * 512 + scol + 4 * jj];
    bv[jj] = *(const float4*)&W[(n0 + srow) * 512 + scol + 4 * jj];
  }

  for (int k0 = 0; k0 < 512; k0 += 64) {
    __syncthreads();
#pragma unroll
    for (int jj = 0; jj < 4; ++jj) {
      ushort4 hh, ll;
      split4(av[jj], hh, ll);
      *(ushort4*)&Ah[srow * 72 + scol + 4 * jj] = hh;
      *(ushort4*)&Al[srow * 72 + scol + 4 * jj] = ll;
      split4(bv[jj], hh, ll);
      *(ushort4*)&Bh[srow * 72 + scol + 4 * jj] = hh;
      *(ushort4*)&Bl[srow * 72 + scol + 4 * jj] = ll;
    }
    __syncthreads();
    if (k0 + 64 < 512) {
#pragma unroll
      for (int jj = 0; jj < 4; ++jj) {
        av[jj] = *(const float4*)&X[(m0 + srow) * 512 + k0 + 64 + scol + 4 * jj];
        bv[jj] = *(const float4*)&W[(n0 + srow) * 512 + k0 + 64 + scol + 4 * jj];
      }
    }
#pragma unroll
    for (int kk = 0; kk < 2; ++kk) {
      short8 ah = *(const short8*)&Ah[(w * 16 + n15) * 72 + kk * 32 + quad * 8];
      short8 al = *(const short8*)&Al[(w * 16 + n15) * 72 + kk * 32 + quad * 8];
#pragma unroll
      for (int nt = 0; nt < 4; ++nt) {
        short8 bh = *(const short8*)&Bh[(nt * 16 + n15) * 72 + kk * 32 + quad * 8];
        short8 bl = *(const short8*)&Bl[(nt * 16 + n15) * 72 + kk * 32 + quad * 8];
        acc[nt] = __builtin_amdgcn_mfma_f32_16x16x32_bf16(ah, bh, acc[nt], 0, 0, 0);
        acc[nt] = __builtin_amdgcn_mfma_f32_16x16x32_bf16(ah, bl, acc[nt], 0, 0, 0);
        acc[nt] = __builtin_amdgcn_mfma_f32_16x16x32_bf16(al, bh, acc[nt], 0, 0, 0);
      }
    }
  }

#pragma unroll
  for (int nt = 0; nt < 4; ++nt) {
    const int j = n0 + nt * 16 + n15;
    const int jj = j & 511;
    const int head = jj >> 6;
    const int hd = jj & 63;
    const float bj = bias[j];
#pragma unroll
    for (int r = 0; r < 4; ++r) {
      const int row = m0 + w * 16 + quad * 4 + r;
      const int t = row >> 3;
      const int batch = row & 7;
      const int i = batch * 8 + head;
      const int idx = ((i << 7) + t) * 64 + hd;
      const float val = acc[nt][r] + bj;
      if (g == 0)      qh[idx] = val * SCALING;
      else if (g == 1) kh[idx] = val;
      else             vh[idx] = bf16r(val);
    }
  }
}

// ---------------------------------------------------------------------------
// Kernel B: one block per (batch,a), now 512 threads / 8 waves (16-wide
// b-strips). Ks LDS staging removed: each lane loads its own k-row segments
// from L2, multiplies by q and packs its MFMA B-fragment in registers (same
// L2 bytes as before, zero LDS traffic for K). biasReg (32 VGPR) feeds the
// MFMA C-operand directly (bias folded in for free). Vs stays double-
// buffered -> one barrier per head. LDS 77824->40960 B, VGPR cap 128:
// 2 blocks x 8 waves = 16 waves/CU (~50% occupancy vs 19.7%).
// ---------------------------------------------------------------------------
__global__ __launch_bounds__(512, 4)
void score_kernel(const float* __restrict__ qh,
                  const float* __restrict__ kh,
                  const unsigned short* __restrict__ vh,
                  const float* __restrict__ cbias,
                  float* __restrict__ attn) {
  __shared__ __align__(16) unsigned short Vs[2][128 * 72];
  __shared__ float rowS[8 * 128];  // fused rows, then softmax weights

  const int ab = blockIdx.x;  // batch*128 + a
  const int batch = ab >> 7;
  const int a = ab & 127;
  const int tid = threadIdx.x;
  const int w = tid >> 6;      // 0..7 : wave == b-strip, later == head
  const int lane = tid & 63;
  const int quad = lane >> 4;
  const int n15 = lane & 15;
  const int col8 = (tid & 7) * 8;   // Vs staging column octet
  const int brow = w * 16 + n15;    // this lane's b row

  // bias fragment preload: bias[b, c] with b = brow, c = ic*16 + quad*4 + r
  const float* __restrict__ bp = cbias + (size_t)ab * 16384;
  f32x4 biasReg[8];
#pragma unroll
  for (int ic = 0; ic < 8; ++ic)
    biasReg[ic] = *(const f32x4*)&bp[brow * 128 + ic * 16 + quad * 4];

  // ---- prologue: head 0 -> B-frags in regs, V -> Vs[0]
  short8 bf0, bf1;
  {
    const int i = batch * 8;
    const float* __restrict__ kb = kh + (size_t)i * 8192;
    const float* __restrict__ qa = qh + ((size_t)i * 128 + a) * 64;
    f32x4 k0a = *(const f32x4*)&kb[brow * 64 + quad * 8];
    f32x4 k0b = *(const f32x4*)&kb[brow * 64 + quad * 8 + 4];
    f32x4 k1a = *(const f32x4*)&kb[brow * 64 + 32 + quad * 8];
    f32x4 k1b = *(const f32x4*)&kb[brow * 64 + 32 + quad * 8 + 4];
    f32x4 q0a = *(const f32x4*)&qa[quad * 8];
    f32x4 q0b = *(const f32x4*)&qa[quad * 8 + 4];
    f32x4 q1a = *(const f32x4*)&qa[32 + quad * 8];
    f32x4 q1b = *(const f32x4*)&qa[32 + quad * 8 + 4];
    k0a *= q0a; k0b *= q0b; k1a *= q1a; k1b *= q1b;
    U4S8 u0, u1;
    u0.u.x = pk_bf16(k0a[0], k0a[1]); u0.u.y = pk_bf16(k0a[2], k0a[3]);
    u0.u.z = pk_bf16(k0b[0], k0b[1]); u0.u.w = pk_bf16(k0b[2], k0b[3]);
    u1.u.x = pk_bf16(k1a[0], k1a[1]); u1.u.y = pk_bf16(k1a[2], k1a[3]);
    u1.u.z = pk_bf16(k1b[0], k1b[1]); u1.u.w = pk_bf16(k1b[2], k1b[3]);
    bf0 = u0.s; bf1 = u1.s;
    const uint4* __restrict__ vb4 = (const uint4*)(vh + (size_t)i * 8192);
    *(uint4*)&Vs[0][(tid >> 3) * 72 + col8] = vb4[tid];
    *(uint4*)&Vs[0][(64 + (tid >> 3)) * 72 + col8] = vb4[512 + tid];
  }
  __syncthreads();

  for (int h = 0; h < 8; ++h) {
    const int buf = h & 1;

    // ---- issue next head's global loads (in flight during MFMA)
    uint4 vreg0, vreg1;
    f32x4 kr0a, kr0b, kr1a, kr1b, qr0a, qr0b, qr1a, qr1b;
    if (h < 7) {
      const int in = batch * 8 + h + 1;
      const float* __restrict__ kb = kh + (size_t)in * 8192;
      const float* __restrict__ qa = qh + ((size_t)in * 128 + a) * 64;
      const uint4* __restrict__ vb4 = (const uint4*)(vh + (size_t)in * 8192);
      vreg0 = vb4[tid];
      vreg1 = vb4[512 + tid];
      kr0a = *(const f32x4*)&kb[brow * 64 + quad * 8];
      kr0b = *(const f32x4*)&kb[brow * 64 + quad * 8 + 4];
      kr1a = *(const f32x4*)&kb[brow * 64 + 32 + quad * 8];
      kr1b = *(const f32x4*)&kb[brow * 64 + 32 + quad * 8 + 4];
      qr0a = *(const f32x4*)&qa[quad * 8];
      qr0b = *(const f32x4*)&qa[quad * 8 + 4];
      qr1a = *(const f32x4*)&qa[32 + quad * 8];
      qr1b = *(const f32x4*)&qa[32 + quad * 8 + 4];
    }

    // ---- MFMA: S^T[c,b] tile column (16 b-cols), bias as C-init (free add)
    f32x4 acc[8];
#pragma unroll
    for (int ic = 0; ic < 8; ++ic) {
      short8 a0 = *(const short8*)&Vs[buf][(ic * 16 + n15) * 72 + quad * 8];
      short8 a1 = *(const short8*)&Vs[buf][(ic * 16 + n15) * 72 + 32 + quad * 8];
      f32x4 t = __builtin_amdgcn_mfma_f32_16x16x32_bf16(a0, bf0, biasReg[ic], 0, 0, 0);
      acc[ic] = __builtin_amdgcn_mfma_f32_16x16x32_bf16(a1, bf1, t, 0, 0, 0);
    }

    // ---- stage next head: V regs -> other buffer, pack next B-frags
    if (h < 7) {
      const int nb = buf ^ 1;
      *(uint4*)&Vs[nb][(tid >> 3) * 72 + col8] = vreg0;
      *(uint4*)&Vs[nb][(64 + (tid >> 3)) * 72 + col8] = vreg1;
      kr0a *= qr0a; kr0b *= qr0b; kr1a *= qr1a; kr1b *= qr1b;
      U4S8 u0, u1;
      u0.u.x = pk_bf16(kr0a[0], kr0a[1]); u0.u.y = pk_bf16(kr0a[2], kr0a[3]);
      u0.u.z = pk_bf16(kr0b[0], kr0b[1]); u0.u.w = pk_bf16(kr0b[2], kr0b[3]);
      u1.u.x = pk_bf16(kr1a[0], kr1a[1]); u1.u.y = pk_bf16(kr1a[2], kr1a[3]);
      u1.u.z = pk_bf16(kr1b[0], kr1b[1]); u1.u.w = pk_bf16(kr1b[2], kr1b[3]);
      bf0 = u0.s; bf1 = u1.s;
    }

    // ---- epilogue: mean/max over c (bias already in acc) -> rowS
    float fsum = 0.f;
    float fmx = -INFINITY;
#pragma unroll
    for (int ic = 0; ic < 8; ++ic) {
      const float v0 = acc[ic][0];
      const float v1 = acc[ic][1];
      const float v2 = acc[ic][2];
      const float v3 = acc[ic][3];
      fsum += (v0 + v1) + (v2 + v3);
      fmx = fmaxf(fmx, fmaxf(fmaxf(v0, v1), fmaxf(v2, v3)));
    }
    fsum += __shfl_xor(fsum, 16, 64);
    fmx = fmaxf(fmx, __shfl_xor(fmx, 16, 64));
    fsum += __shfl_xor(fsum, 32, 64);
    fmx = fmaxf(fmx, __shfl_xor(fmx, 32, 64));
    if (quad == 0) rowS[h * 128 + w * 16 + n15] = fsum * (1.0f / 128.0f) + fmx;

    __syncthreads();  // Vs[nb] visible; all Vs[buf] reads done; rowS visible
  }

  // ---- fused tail: wave w == head w; softmax over b + attn bmm vs L2-hot qh
  {
    const int h = w;
    const int i = batch * 8 + h;
    float f0 = rowS[h * 128 + lane], f1 = rowS[h * 128 + 64 + lane];
    float m = fmaxf(f0, f1);
#pragma unroll
    for (int off = 32; off >= 1; off >>= 1) m = fmaxf(m, __shfl_xor(m, off, 64));
    const float e0 = expf(f0 - m), e1 = expf(f1 - m);
    float s = e0 + e1;
#pragma unroll
    for (int off = 32; off >= 1; off >>= 1) s += __shfl_xor(s, off, 64);
    const float inv = 1.0f / s;
    rowS[h * 128 + lane] = e0 * inv;       // same wave produces & consumes:
    rowS[h * 128 + 64 + lane] = e1 * inv;  // no barrier needed
    const float* __restrict__ qp = qh + (size_t)i * 8192 + lane;
    float acc2 = 0.0f;
#pragma unroll 8
    for (int b = 0; b < 128; ++b)
      acc2 = fmaf(rowS[h * 128 + b], qp[b * 64], acc2);
    attn[((size_t)a * 8 + batch) * 512 + h * 64 + lane] = acc2;
  }
}

// ---------------------------------------------------------------------------
// Kernel D: output projection, hi/lo MFMA; 64m x 32n tiles -> 256 blocks.
// Unchanged.
// ---------------------------------------------------------------------------
__global__ __launch_bounds__(256)
void outmm_kernel(const float* __restrict__ Xa,
                  const float* __restrict__ W,
                  const float* __restrict__ bias,
                  float* __restrict__ out) {
  __shared__ __align__(16) unsigned short Ah[64 * 72];
  __shared__ __align__(16) unsigned short Al[64 * 72];
  __shared__ __align__(16) unsigned short Bh[32 * 72];
  __shared__ __align__(16) unsigned short Bl[32 * 72];
  const int n0 = blockIdx.x * 32;  // 0..480
  const int m0 = blockIdx.y * 64;  // 0..960
  const int tid = threadIdx.x;
  const int w = tid >> 6, lane = tid & 63;
  const int quad = lane >> 4, n15 = lane & 15;
  const int srow = tid >> 2;        // 0..63 (A rows)
  const int scol = (tid & 3) * 16;  // 0,16,32,48
  const bool doB = tid >= 128;
  const int brow = (tid & 127) >> 2;   // 0..31 (B rows, waves 2-3)
  const int bcol = (tid & 3) * 16;

  f32x4 acc[2];
#pragma unroll
  for (int nt = 0; nt < 2; ++nt) acc[nt] = (f32x4){0.f, 0.f, 0.f, 0.f};

  float4 av[4], bv[4];
#pragma unroll
  for (int jj = 0; jj < 4; ++jj)
    av[jj] = *(const float4*)&Xa[(m0 + srow) * 512 + scol + 4 * jj];
  if (doB) {
#pragma unroll
    for (int jj = 0; jj < 4; ++jj)
      bv[jj] = *(const float4*)&W[(n0 + brow) * 512 + bcol + 4 * jj];
  }

  for (int k0 = 0; k0 < 512; k0 += 64) {
    __syncthreads();
#pragma unroll
    for (int jj = 0; jj < 4; ++jj) {
      ushort4 hh, ll;
      split4(av[jj], hh, ll);
      *(ushort4*)&Ah[srow * 72 + scol + 4 * jj] = hh;
      *(ushort4*)&Al[srow * 72 + scol + 4 * jj] = ll;
    }
    if (doB) {
#pragma unroll
      for (int jj = 0; jj < 4; ++jj) {
        ushort4 hh, ll;
        split4(bv[jj], hh, ll);
        *(ushort4*)&Bh[brow * 72 + bcol + 4 * jj] = hh;
        *(ushort4*)&Bl[brow * 72 + bcol + 4 * jj] = ll;
      }
    }
    __syncthreads();
    if (k0 + 64 < 512) {
#pragma unroll
      for (int jj = 0; jj < 4; ++jj)
        av[jj] = *(const float4*)&Xa[(m0 + srow) * 512 + k0 + 64 + scol + 4 * jj];
      if (doB) {
#pragma unroll
        for (int jj = 0; jj < 4; ++jj)
          bv[jj] = *(const float4*)&W[(n0 + brow) * 512 + k0 + 64 + bcol + 4 * jj];
      }
    }
#pragma unroll
    for (int kk = 0; kk < 2; ++kk) {
      short8 ah = *(const short8*)&Ah[(w * 16 + n15) * 72 + kk * 32 + quad * 8];
      short8 al = *(const short8*)&Al[(w * 16 + n15) * 72 + kk * 32 + quad * 8];
#pragma unroll
      for (int nt = 0; nt < 2; ++nt) {
        short8 bh = *(const short8*)&Bh[(nt * 16 + n15) * 72 + kk * 32 + quad * 8];
        short8 bl = *(const short8*)&Bl[(nt * 16 + n15) * 72 + kk * 32 + quad * 8];
        acc[nt] = __builtin_amdgcn_mfma_f32_16x16x32_bf16(ah, bh, acc[nt], 0, 0, 0);
        acc[nt] = __builtin_amdgcn_mfma_f32_16x16x32_bf16(ah, bl, acc[nt], 0, 0, 0);
        acc[nt] = __builtin_amdgcn_mfma_f32_16x16x32_bf16(al, bh, acc[nt], 0, 0, 0);
      }
    }
  }

#pragma unroll
  for (int nt = 0; nt < 2; ++nt) {
    const int j = n0 + nt * 16 + n15;
    const float bj = bias[j];
#pragma unroll
    for (int r = 0; r < 4; ++r) {
      const int row = m0 + w * 16 + quad * 4 + r;
      out[(size_t)row * 512 + j] = acc[nt][r] + bj;
    }
  }
}

extern "C" void kernel_launch(void* const* d_in, const int* in_sizes, int n_in,
                              void* d_out, int out_size, void* d_ws,
                              size_t ws_size, hipStream_t stream) {
  const float* query = (const float*)d_in[0];
  const float* key   = (const float*)d_in[1];
  const float* value = (const float*)d_in[2];
  const float* cbias = (const float*)d_in[3];
  const float* W     = (const float*)d_in[4];
  const float* pb    = (const float*)d_in[5];
  const float* out_w = (const float*)d_in[6];
  const float* out_b = (const float*)d_in[7];
  float* out = (float*)d_out;

  float* ws = (float*)d_ws;
  float* qh = ws;                                        // 524288 f
  float* kh = ws + 524288;                               // 524288 f
  unsigned short* vh = (unsigned short*)(ws + 1048576);  // 524288 bf16
  float* attn = ws + 1048576 + 262144;                   // 524288 f

  projmm_kernel<<<dim3(24, 16), 256, 0, stream>>>(query, key, value, W, pb,
                                                  qh, kh, vh);
  score_kernel<<<1024, 512, 0, stream>>>(qh, kh, vh, cbias, attn);
  outmm_kernel<<<dim3(16, 16), 256, 0, stream>>>(attn, out_w, out_b, out);
}